// Round 14
// baseline (408.526 us; speedup 1.0000x reference)
//
#include <hip/hip_runtime.h>

typedef short short8 __attribute__((ext_vector_type(8)));
typedef float f32x4 __attribute__((ext_vector_type(4)));
typedef unsigned long long u64;

#define NE 1024
#define D 64
#define HW 4096
#define NTOK 65536
#define MARGIN 4.0e-3f     // chunk-local margin, proven R6/R7 (absmax 0.0)
#define FLT_MAX_F 3.402823466e+38f

// ws (<=262KB proven): bn f32[1024]@0 ; ebf u16[65536]@4096 ; win u16[65536]@135168
#define WS_BN  0
#define WS_EBF 4096
#define WS_WIN 135168
// d_out overlay (exactly 16MB, fully overwritten by k3_gather):
//   mask u64[65536*16] @0 (8MB) ; frag short8[524288] @8388608 (8MB)

__device__ __forceinline__ unsigned short f2bf(float f) {   // RNE f32->bf16
    unsigned u = __float_as_uint(f);
    return (unsigned short)((u + 0x7fffu + ((u >> 16) & 1u)) >> 16);
}

// numpy pairwise sum of squares, n=64 (frozen — exact since R2)
__device__ __forceinline__ float np_sum64_sq(const float* v) {
    float s[8];
#pragma unroll
    for (int j = 0; j < 8; ++j) s[j] = __fmul_rn(v[j], v[j]);
#pragma unroll
    for (int i = 8; i < 64; i += 8) {
#pragma unroll
        for (int j = 0; j < 8; ++j)
            s[j] = __fadd_rn(s[j], __fmul_rn(v[i + j], v[i + j]));
    }
    return __fadd_rn(__fadd_rn(__fadd_rn(s[0], s[1]), __fadd_rn(s[2], s[3])),
                     __fadd_rn(__fadd_rn(s[4], s[5]), __fadd_rn(s[6], s[7])));
}

// fused prep: zero mask, bf16 codebook, norms, AND one B-fragment per thread
// (fragment build + layout byte-identical to R6-proven kP_prep)
__global__ __launch_bounds__(256) void kF_prep(
        const float* __restrict__ in, const float* __restrict__ cb,
        float* __restrict__ bn, unsigned short* __restrict__ ebf,
        u64* __restrict__ mask, short8* __restrict__ frag) {
    const int gid = blockIdx.x * 256 + threadIdx.x;     // 524288 threads
    ((int4*)mask)[gid] = int4{0, 0, 0, 0};              // zero 8 MB mask
    if (gid < NE * D) ebf[gid] = f2bf(cb[gid]);
    if (gid < NE) {
        float row[D];
        const float4* r4 = reinterpret_cast<const float4*>(cb + (size_t)gid * D);
#pragma unroll
        for (int i = 0; i < 16; ++i) {
            float4 v = r4[i];
            row[4*i+0] = v.x; row[4*i+1] = v.y; row[4*i+2] = v.z; row[4*i+3] = v.w;
        }
        bn[gid] = np_sum64_sq(row);
    }
    const int slot = gid >> 2, j = gid & 3;
    const int tid_o = slot & 255, tg = slot >> 8;
    const int w = tid_o >> 6, lane = tid_o & 63;
    const int lcol = lane & 15, lhi = lane >> 4;
    const int tokw = tg * 128 + w * 32;
    const int b = tokw >> 12, hwb = tokw & 4095;
    const int hw = hwb + ((j & 2) ? 16 : 0) + lcol;
    const int kb = lhi * 8 + ((j & 1) ? 32 : 0);
    const float* p = in + (size_t)b * (D * HW) + (size_t)kb * HW + hw;
    short8 B;
#pragma unroll
    for (int j2 = 0; j2 < 8; ++j2) B[j2] = (short)f2bf(p[(size_t)j2 * HW]);
    frag[gid] = B;
}

// single-pass score+mark: chunk-local threshold (R6/R7-proven superset),
// t-values held in registers, sparse fire-and-forget atomicOr marks.
__global__ __launch_bounds__(256, 4) void k1_score(
        const unsigned short* __restrict__ ebf, const float* __restrict__ bn_g,
        const short8* __restrict__ frag, u64* __restrict__ mask) {
    __shared__ unsigned short ebq[128 * 64];   // 16 KiB, XOR-swizzled (proven)
    __shared__ float sbn[128];

    // XCD-contiguous: XCD x gets token-groups [64x,64x+64), all 8 chunks
    const int sw  = (blockIdx.x & 7) * 512 + (blockIdx.x >> 3);
    const int tg  = sw >> 3;
    const int c   = sw & 7;
    const int tid  = threadIdx.x;
    const int lane = tid & 63, w = tid >> 6;
    const int lcol = lane & 15, lhi = lane >> 4, lrow = lhi * 4;
    const int tokw = tg * 128 + w * 32;

    if (tid < 128) sbn[tid] = bn_g[c * 128 + tid];
    const char* src = (const char*)(ebf + (size_t)c * 128 * 64);
#pragma unroll
    for (int i = 0; i < 4; ++i) {
        int L = (tid + i * 256) * 16;
        int row = L >> 7, wi = L & 127;
        int4 v = *(const int4*)(src + L);
        *(int4*)((char*)ebq + row * 128 + (wi ^ ((row & 7) << 4))) = v;
    }
    // fragments: 4 contiguous dwordx4 loads (built by kF_prep, R6-proven layout)
    const short8* fp = frag + ((size_t)tg * 256 + tid) * 4;
    short8 B00 = fp[0], B01 = fp[1], B10 = fp[2], B11 = fp[3];
    __syncthreads();

    const int swz   = (lcol & 7) << 4;
    const int aoff0 = lcol * 128 + ((lhi * 16) ^ swz);
    const int aoff1 = lcol * 128 + ((64 + lhi * 16) ^ swz);

    // single MFMA pass; t-values in registers (constant-indexed, R8 pattern)
    float t0a[32], t1a[32];
    float v10 = FLT_MAX_F, v11 = FLT_MAX_F;
#pragma unroll
    for (int ct = 0; ct < 8; ++ct) {
        const char* lp = (const char*)ebq + ct * 2048;
        short8 A0 = *(const short8*)(lp + aoff0);
        short8 A1 = *(const short8*)(lp + aoff1);
        f32x4 bnv = *(const f32x4*)(sbn + ct * 16 + lrow);
        f32x4 acc = {0.f, 0.f, 0.f, 0.f};
        acc = __builtin_amdgcn_mfma_f32_16x16x32_bf16(A0, B00, acc, 0, 0, 0);
        acc = __builtin_amdgcn_mfma_f32_16x16x32_bf16(A1, B01, acc, 0, 0, 0);
        f32x4 ac2 = {0.f, 0.f, 0.f, 0.f};
        ac2 = __builtin_amdgcn_mfma_f32_16x16x32_bf16(A0, B10, ac2, 0, 0, 0);
        ac2 = __builtin_amdgcn_mfma_f32_16x16x32_bf16(A1, B11, ac2, 0, 0, 0);
#pragma unroll
        for (int r = 0; r < 4; ++r) {
            float t0 = __fmaf_rn(-2.0f, acc[r], bnv[r]);
            t0a[ct * 4 + r] = t0; v10 = fminf(v10, t0);
            float t1 = __fmaf_rn(-2.0f, ac2[r], bnv[r]);
            t1a[ct * 4 + r] = t1; v11 = fminf(v11, t1);
        }
    }
    v10 = fminf(v10, __shfl_xor(v10, 16)); v10 = fminf(v10, __shfl_xor(v10, 32));
    v11 = fminf(v11, __shfl_xor(v11, 16)); v11 = fminf(v11, __shfl_xor(v11, 32));
    // chunk-local margin superset (R6 proof): M >= 2*bf16err -> np-winner marked
    const float thr0 = v10 + MARGIN, thr1 = v11 + MARGIN;
    u64* mrow0 = mask + (size_t)(tokw + lcol) * 16;
    u64* mrow1 = mask + (size_t)(tokw + 16 + lcol) * 16;
#pragma unroll
    for (int i = 0; i < 32; ++i) {
        const int kg = c * 128 + (i >> 2) * 16 + lrow + (i & 3);
        if (t0a[i] <= thr0) atomicOr(&mrow0[kg >> 6], 1ull << (kg & 63));
        if (t1a[i] <= thr1) atomicOr(&mrow1[kg >> 6], 1ull << (kg & 63));
    }
}

// 8 threads per token: frozen-exact rerank; u64 (q,k) key min is
// order-independent -> split+reduce is semantics-preserving (proven R13)
__global__ __launch_bounds__(256, 4) void k2_rerank(
        const float* __restrict__ in, const float* __restrict__ cb,
        const float* __restrict__ bn, const u64* __restrict__ mask,
        unsigned short* __restrict__ win) {
    const int gid = blockIdx.x * 256 + threadIdx.x;   // 524288 threads
    const int tok = gid >> 3, sub = gid & 7;
    const int b = tok >> 12, hw = tok & 4095;
    const float* x = in + (size_t)b * (D * HW) + hw;
    float xv[D];
#pragma unroll
    for (int d = 0; d < D; ++d) xv[d] = x[(size_t)d * HW];   // 8 lanes share lines
    const float a = np_sum64_sq(xv);                          // frozen

    u64 best = ~0ull;
    int kp = -1;
    int pos = 0;
    for (int wd = 0; wd < 16; ++wd) {
        u64 m = mask[(size_t)tok * 16 + wd];
        while (m) {
            const int k = wd * 64 + (int)__builtin_ctzll(m);
            m &= m - 1;
            if (((pos++) & 7) != sub) continue;
            if (kp < 0) { kp = k; continue; }
            // pair: two independent frozen chains (each sequential asc d)
            const float* e0 = cb + (size_t)kp * D;
            const float* e1 = cb + (size_t)k * D;
            float d0 = 0.f, d1 = 0.f;
#pragma unroll
            for (int d = 0; d < 64; ++d) {
                d0 = __fmaf_rn(xv[d], e0[d], d0);
                d1 = __fmaf_rn(xv[d], e1[d], d1);
            }
            float q0 = __fsub_rn(__fadd_rn(a, bn[kp]), __fmul_rn(2.0f, d0));  // frozen
            float q1 = __fsub_rn(__fadd_rn(a, bn[k]),  __fmul_rn(2.0f, d1));  // frozen
            u64 key0 = (((u64)__float_as_uint(q0)) << 32) | (unsigned)kp;
            u64 key1 = (((u64)__float_as_uint(q1)) << 32) | (unsigned)k;
            u64 kmin = key0 < key1 ? key0 : key1;
            best = best < kmin ? best : kmin;
            kp = -1;
        }
    }
    if (kp >= 0) {                              // leftover single
        const float* e0 = cb + (size_t)kp * D;
        float d0 = 0.f;
#pragma unroll
        for (int d = 0; d < 64; ++d) d0 = __fmaf_rn(xv[d], e0[d], d0);
        float q0 = __fsub_rn(__fadd_rn(a, bn[kp]), __fmul_rn(2.0f, d0));
        u64 key0 = (((u64)__float_as_uint(q0)) << 32) | (unsigned)kp;
        best = best < key0 ? best : key0;
    }
#pragma unroll
    for (int o = 1; o < 8; o <<= 1) {
        u64 v = __shfl_xor(best, o);
        best = best < v ? best : v;
    }
    if (sub == 0) win[tok] = (unsigned short)(best & 0x3FFull);
}

__global__ __launch_bounds__(256) void k3_gather(
        const float* __restrict__ cb, const unsigned short* __restrict__ win,
        float* __restrict__ out) {
    const int gid = blockIdx.x * 256 + threadIdx.x;   // 262144 threads
    const int tok = gid >> 2, qd = (gid & 3) << 4;
    const int b = tok >> 12, hw = tok & 4095;
    const unsigned k = win[tok];
    const float4* er = reinterpret_cast<const float4*>(cb + (size_t)k * D + qd);
    float* ot = out + (size_t)b * (D * HW) + hw;
#pragma unroll
    for (int i = 0; i < 4; ++i) {
        float4 e = er[i];
        ot[(size_t)(qd + 4*i + 0) * HW] = e.x;
        ot[(size_t)(qd + 4*i + 1) * HW] = e.y;
        ot[(size_t)(qd + 4*i + 2) * HW] = e.z;
        ot[(size_t)(qd + 4*i + 3) * HW] = e.w;
    }
}

extern "C" void kernel_launch(void* const* d_in, const int* in_sizes, int n_in,
                              void* d_out, int out_size, void* d_ws, size_t ws_size,
                              hipStream_t stream) {
    const float* in  = (const float*)d_in[0];
    const float* cb  = (const float*)d_in[1];
    float*       out = (float*)d_out;
    char*        ws  = (char*)d_ws;

    float*          bn   = (float*)(ws + WS_BN);
    unsigned short* ebf  = (unsigned short*)(ws + WS_EBF);
    unsigned short* win  = (unsigned short*)(ws + WS_WIN);
    u64*            mask = (u64*)d_out;
    short8*         frag = (short8*)((char*)d_out + 8388608);

    hipLaunchKernelGGL(kF_prep,   dim3(2048), dim3(256), 0, stream, in, cb, bn, ebf, mask, frag);
    hipLaunchKernelGGL(k1_score,  dim3(4096), dim3(256), 0, stream, ebf, bn, frag, mask);
    hipLaunchKernelGGL(k2_rerank, dim3(2048), dim3(256), 0, stream, in, cb, bn, mask, win);
    hipLaunchKernelGGL(k3_gather, dim3(1024), dim3(256), 0, stream, cb, win, out);
}

// Round 15
// 81.953 us; speedup vs baseline: 4.9849x; 4.9849x over previous
//
#include <hip/hip_runtime.h>

typedef short short8 __attribute__((ext_vector_type(8)));
typedef float f32x4 __attribute__((ext_vector_type(4)));
typedef unsigned long long u64;

#define NE 1024
#define D 64
#define HW 4096
#define NTOK 65536
#define MARGIN 3.0e-3f     // global-threshold margin (proven R3/R5/R12/R13)
#define FLT_MAX_F 3.402823466e+38f

// ws (256 MiB evident; we use 528 KB):
//   bn f32[1024]@0 ; ebf u16[65536]@4096 ; win u16[65536]@135168 ; gmin u32[65536]@266240
#define WS_BN   0
#define WS_EBF  4096
#define WS_WIN  135168
#define WS_GMIN 266240
// d_out overlay (16 MB, fully overwritten by k3_gather):
//   mask u64[65536*16] @0 (8MB) ; frag short8[524288] @8388608 (8MB)

__device__ __forceinline__ unsigned short f2bf(float f) {   // RNE f32->bf16
    unsigned u = __float_as_uint(f);
    return (unsigned short)((u + 0x7fffu + ((u >> 16) & 1u)) >> 16);
}

// order-preserving f32 <-> u32 bijection (R10 bugfix, proven R12/R13)
__device__ __forceinline__ unsigned fenc(float f) {
    unsigned u = __float_as_uint(f);
    return (u & 0x80000000u) ? ~u : (u | 0x80000000u);
}
__device__ __forceinline__ float fdec(unsigned u) {
    unsigned v = (u & 0x80000000u) ? (u & 0x7FFFFFFFu) : ~u;
    return __uint_as_float(v);
}

// numpy pairwise sum of squares, n=64 (frozen — exact since R2)
__device__ __forceinline__ float np_sum64_sq(const float* v) {
    float s[8];
#pragma unroll
    for (int j = 0; j < 8; ++j) s[j] = __fmul_rn(v[j], v[j]);
#pragma unroll
    for (int i = 8; i < 64; i += 8) {
#pragma unroll
        for (int j = 0; j < 8; ++j)
            s[j] = __fadd_rn(s[j], __fmul_rn(v[i + j], v[i + j]));
    }
    return __fadd_rn(__fadd_rn(__fadd_rn(s[0], s[1]), __fadd_rn(s[2], s[3])),
                     __fadd_rn(__fadd_rn(s[4], s[5]), __fadd_rn(s[6], s[7])));
}

// fused prep: zero mask, init gmin, bf16 codebook, norms, one B-fragment/thread
// (fragment build + layout byte-identical to R6/R14-proven kP/kF)
__global__ __launch_bounds__(256) void kF_prep(
        const float* __restrict__ in, const float* __restrict__ cb,
        float* __restrict__ bn, unsigned short* __restrict__ ebf,
        u64* __restrict__ mask, short8* __restrict__ frag,
        unsigned* __restrict__ gmin) {
    const int gid = blockIdx.x * 256 + threadIdx.x;     // 524288 threads
    ((int4*)mask)[gid] = int4{0, 0, 0, 0};              // zero 8 MB mask
    if (gid < NTOK) gmin[gid] = 0xFFFFFFFFu;            // max encoded value
    if (gid < NE * D) ebf[gid] = f2bf(cb[gid]);
    if (gid < NE) {
        float row[D];
        const float4* r4 = reinterpret_cast<const float4*>(cb + (size_t)gid * D);
#pragma unroll
        for (int i = 0; i < 16; ++i) {
            float4 v = r4[i];
            row[4*i+0] = v.x; row[4*i+1] = v.y; row[4*i+2] = v.z; row[4*i+3] = v.w;
        }
        bn[gid] = np_sum64_sq(row);
    }
    const int slot = gid >> 2, j = gid & 3;
    const int tid_o = slot & 255, tg = slot >> 8;
    const int w = tid_o >> 6, lane = tid_o & 63;
    const int lcol = lane & 15, lhi = lane >> 4;
    const int tokw = tg * 128 + w * 32;
    const int b = tokw >> 12, hwb = tokw & 4095;
    const int hw = hwb + ((j & 2) ? 16 : 0) + lcol;
    const int kb = lhi * 8 + ((j & 1) ? 32 : 0);
    const float* p = in + (size_t)b * (D * HW) + (size_t)kb * HW + hw;
    short8 B;
#pragma unroll
    for (int j2 = 0; j2 < 8; ++j2) B[j2] = (short)f2bf(p[(size_t)j2 * HW]);
    frag[gid] = B;
}

// ---- shared k1 body (staging + frag loads; no input reads) ----
#define K1_HEAD                                                               \
    __shared__ unsigned short ebq[128 * 64];                                  \
    __shared__ float sbn[128];                                                \
    const int sw  = (blockIdx.x & 7) * 512 + (blockIdx.x >> 3);               \
    const int tg  = sw >> 3;                                                  \
    const int c   = sw & 7;                                                   \
    const int tid  = threadIdx.x;                                             \
    const int lane = tid & 63, w = tid >> 6;                                  \
    const int lcol = lane & 15, lhi = lane >> 4, lrow = lhi * 4;              \
    const int tokw = tg * 128 + w * 32;                                       \
    if (tid < 128) sbn[tid] = bn_g[c * 128 + tid];                            \
    const char* src = (const char*)(ebf + (size_t)c * 128 * 64);              \
    _Pragma("unroll")                                                         \
    for (int i = 0; i < 4; ++i) {                                             \
        int L = (tid + i * 256) * 16;                                         \
        int row = L >> 7, wi = L & 127;                                       \
        int4 v = *(const int4*)(src + L);                                     \
        *(int4*)((char*)ebq + row * 128 + (wi ^ ((row & 7) << 4))) = v;       \
    }                                                                         \
    const short8* fp = frag + ((size_t)tg * 256 + tid) * 4;                   \
    short8 B00 = fp[0], B01 = fp[1], B10 = fp[2], B11 = fp[3];                \
    __syncthreads();                                                          \
    const int swz   = (lcol & 7) << 4;                                        \
    const int aoff0 = lcol * 128 + ((lhi * 16) ^ swz);                        \
    const int aoff1 = lcol * 128 + ((64 + lhi * 16) ^ swz);

#define K1_MFMA(CT)                                                           \
    const char* lp = (const char*)ebq + (CT) * 2048;                          \
    short8 A0 = *(const short8*)(lp + aoff0);                                 \
    short8 A1 = *(const short8*)(lp + aoff1);                                 \
    f32x4 bnv = *(const f32x4*)(sbn + (CT) * 16 + lrow);                      \
    f32x4 acc = {0.f, 0.f, 0.f, 0.f};                                         \
    acc = __builtin_amdgcn_mfma_f32_16x16x32_bf16(A0, B00, acc, 0, 0, 0);     \
    acc = __builtin_amdgcn_mfma_f32_16x16x32_bf16(A1, B01, acc, 0, 0, 0);     \
    f32x4 ac2 = {0.f, 0.f, 0.f, 0.f};                                         \
    ac2 = __builtin_amdgcn_mfma_f32_16x16x32_bf16(A0, B10, ac2, 0, 0, 0);     \
    ac2 = __builtin_amdgcn_mfma_f32_16x16x32_bf16(A1, B11, ac2, 0, 0, 0);

// pass A: per-token chunk-min -> atomicMin(gmin) (fire-and-forget, fenc'd)
__global__ __launch_bounds__(256, 4) void k1a_min(
        const unsigned short* __restrict__ ebf, const float* __restrict__ bn_g,
        const short8* __restrict__ frag, unsigned* __restrict__ gmin) {
    K1_HEAD
    float v10 = FLT_MAX_F, v11 = FLT_MAX_F;
#pragma unroll
    for (int ct = 0; ct < 8; ++ct) {
        K1_MFMA(ct)
#pragma unroll
        for (int r = 0; r < 4; ++r) {
            v10 = fminf(v10, __fmaf_rn(-2.0f, acc[r], bnv[r]));
            v11 = fminf(v11, __fmaf_rn(-2.0f, ac2[r], bnv[r]));
        }
    }
    v10 = fminf(v10, __shfl_xor(v10, 16)); v10 = fminf(v10, __shfl_xor(v10, 32));
    v11 = fminf(v11, __shfl_xor(v11, 16)); v11 = fminf(v11, __shfl_xor(v11, 32));
    if (lhi == 0) atomicMin(&gmin[tokw + lcol],      fenc(v10));
    if (lhi == 1) atomicMin(&gmin[tokw + 16 + lcol], fenc(v11));
}

// pass B: recompute t (bit-identical) and mark t <= gmin+MARGIN into bitmask
__global__ __launch_bounds__(256, 4) void k1b_mark(
        const unsigned short* __restrict__ ebf, const float* __restrict__ bn_g,
        const short8* __restrict__ frag, const unsigned* __restrict__ gmin,
        u64* __restrict__ mask) {
    K1_HEAD
    const float thr0 = fdec(gmin[tokw + lcol]) + MARGIN;
    const float thr1 = fdec(gmin[tokw + 16 + lcol]) + MARGIN;
    u64* mrow0 = mask + (size_t)(tokw + lcol) * 16;
    u64* mrow1 = mask + (size_t)(tokw + 16 + lcol) * 16;
#pragma unroll
    for (int ct = 0; ct < 8; ++ct) {
        K1_MFMA(ct)
        const int kg = c * 128 + ct * 16 + lrow;
#pragma unroll
        for (int r = 0; r < 4; ++r) {
            float t0 = __fmaf_rn(-2.0f, acc[r], bnv[r]);
            if (t0 <= thr0) atomicOr(&mrow0[(kg + r) >> 6], 1ull << ((kg + r) & 63));
            float t1 = __fmaf_rn(-2.0f, ac2[r], bnv[r]);
            if (t1 <= thr1) atomicOr(&mrow1[(kg + r) >> 6], 1ull << ((kg + r) & 63));
        }
    }
}

// 8 threads per token (proven R13): frozen-exact rerank; u64 (q,k) key min
__global__ __launch_bounds__(256, 4) void k2_rerank(
        const float* __restrict__ in, const float* __restrict__ cb,
        const float* __restrict__ bn, const u64* __restrict__ mask,
        unsigned short* __restrict__ win) {
    const int gid = blockIdx.x * 256 + threadIdx.x;   // 524288 threads
    const int tok = gid >> 3, sub = gid & 7;
    const int b = tok >> 12, hw = tok & 4095;
    const float* x = in + (size_t)b * (D * HW) + hw;
    float xv[D];
#pragma unroll
    for (int d = 0; d < D; ++d) xv[d] = x[(size_t)d * HW];   // 8 lanes share lines
    const float a = np_sum64_sq(xv);                          // frozen

    u64 best = ~0ull;
    int kp = -1;
    int pos = 0;
    for (int wd = 0; wd < 16; ++wd) {
        u64 m = mask[(size_t)tok * 16 + wd];
        while (m) {
            const int k = wd * 64 + (int)__builtin_ctzll(m);
            m &= m - 1;
            if (((pos++) & 7) != sub) continue;
            if (kp < 0) { kp = k; continue; }
            const float* e0 = cb + (size_t)kp * D;
            const float* e1 = cb + (size_t)k * D;
            float d0 = 0.f, d1 = 0.f;
#pragma unroll
            for (int d = 0; d < 64; ++d) {
                d0 = __fmaf_rn(xv[d], e0[d], d0);
                d1 = __fmaf_rn(xv[d], e1[d], d1);
            }
            float q0 = __fsub_rn(__fadd_rn(a, bn[kp]), __fmul_rn(2.0f, d0));  // frozen
            float q1 = __fsub_rn(__fadd_rn(a, bn[k]),  __fmul_rn(2.0f, d1));  // frozen
            u64 key0 = (((u64)__float_as_uint(q0)) << 32) | (unsigned)kp;
            u64 key1 = (((u64)__float_as_uint(q1)) << 32) | (unsigned)k;
            u64 kmin = key0 < key1 ? key0 : key1;
            best = best < kmin ? best : kmin;
            kp = -1;
        }
    }
    if (kp >= 0) {
        const float* e0 = cb + (size_t)kp * D;
        float d0 = 0.f;
#pragma unroll
        for (int d = 0; d < 64; ++d) d0 = __fmaf_rn(xv[d], e0[d], d0);
        float q0 = __fsub_rn(__fadd_rn(a, bn[kp]), __fmul_rn(2.0f, d0));
        u64 key0 = (((u64)__float_as_uint(q0)) << 32) | (unsigned)kp;
        best = best < key0 ? best : key0;
    }
#pragma unroll
    for (int o = 1; o < 8; o <<= 1) {
        u64 v = __shfl_xor(best, o);
        best = best < v ? best : v;
    }
    if (sub == 0) win[tok] = (unsigned short)(best & 0x3FFull);
}

__global__ __launch_bounds__(256) void k3_gather(
        const float* __restrict__ cb, const unsigned short* __restrict__ win,
        float* __restrict__ out) {
    const int gid = blockIdx.x * 256 + threadIdx.x;   // 262144 threads
    const int tok = gid >> 2, qd = (gid & 3) << 4;
    const int b = tok >> 12, hw = tok & 4095;
    const unsigned k = win[tok];
    const float4* er = reinterpret_cast<const float4*>(cb + (size_t)k * D + qd);
    float* ot = out + (size_t)b * (D * HW) + hw;
#pragma unroll
    for (int i = 0; i < 4; ++i) {
        float4 e = er[i];
        ot[(size_t)(qd + 4*i + 0) * HW] = e.x;
        ot[(size_t)(qd + 4*i + 1) * HW] = e.y;
        ot[(size_t)(qd + 4*i + 2) * HW] = e.z;
        ot[(size_t)(qd + 4*i + 3) * HW] = e.w;
    }
}

extern "C" void kernel_launch(void* const* d_in, const int* in_sizes, int n_in,
                              void* d_out, int out_size, void* d_ws, size_t ws_size,
                              hipStream_t stream) {
    const float* in  = (const float*)d_in[0];
    const float* cb  = (const float*)d_in[1];
    float*       out = (float*)d_out;
    char*        ws  = (char*)d_ws;

    float*          bn   = (float*)(ws + WS_BN);
    unsigned short* ebf  = (unsigned short*)(ws + WS_EBF);
    unsigned short* win  = (unsigned short*)(ws + WS_WIN);
    unsigned*       gmin = (unsigned*)(ws + WS_GMIN);
    u64*            mask = (u64*)d_out;
    short8*         frag = (short8*)((char*)d_out + 8388608);

    hipLaunchKernelGGL(kF_prep,   dim3(2048), dim3(256), 0, stream, in, cb, bn, ebf, mask, frag, gmin);
    hipLaunchKernelGGL(k1a_min,   dim3(4096), dim3(256), 0, stream, ebf, bn, frag, gmin);
    hipLaunchKernelGGL(k1b_mark,  dim3(4096), dim3(256), 0, stream, ebf, bn, frag, gmin, mask);
    hipLaunchKernelGGL(k2_rerank, dim3(2048), dim3(256), 0, stream, in, cb, bn, mask, win);
    hipLaunchKernelGGL(k3_gather, dim3(1024), dim3(256), 0, stream, cb, win, out);
}